// Round 1
// 731.790 us; speedup vs baseline: 2.6169x; 2.6169x over previous
//
#include <hip/hip_runtime.h>

// IndexAddInplace: out = x.at[idx].add(src)
//   x   : (100000, 512) f32
//   idx : (200000,)     int32 (harness passes integers as int)
//   src : (200000, 512) f32
//
// v2: scatter-atomics -> inverse-mapping gather.
// Old version: 102.4M fp32 global atomics = 77 G atomics/s ceiling (17% HBM,
// WRITE_SIZE showed 16B/atomic RMW amplification). New version builds
// dst->src buckets on device (histogram + scan + fill over 200k ints),
// then one block per dst row computes out[row] = x[row] + sum(src rows).
// HBM traffic floor: 204.8 (x) + 409.6 (src) + 204.8 (out) = 819 MB.

#define D        512
#define D_VEC4   128          // 512 / 4
#define N_DST    100000
#define N_SRC    200000

#define SCAN_BLK 1024
#define NB_SCAN  ((N_DST + SCAN_BLK - 1) / SCAN_BLK)   // 98

// ---------------- inverse-map construction (tiny kernels) ----------------

__global__ void ia_hist(const int* __restrict__ idx, int* __restrict__ counts) {
    int i = blockIdx.x * blockDim.x + threadIdx.x;
    if (i < N_SRC) atomicAdd(&counts[idx[i]], 1);
}

// Per-block exclusive scan of counts -> offsets; per-block totals -> bsums.
__global__ void ia_scan_block(const int* __restrict__ counts,
                              int* __restrict__ offsets,
                              int* __restrict__ bsums) {
    __shared__ int tmp[SCAN_BLK];
    int tid = threadIdx.x;
    int i   = blockIdx.x * SCAN_BLK + tid;
    int v   = (i < N_DST) ? counts[i] : 0;
    tmp[tid] = v;
    __syncthreads();
    // Hillis-Steele inclusive scan (read-all then write-all per step)
    for (int d = 1; d < SCAN_BLK; d <<= 1) {
        int t = (tid >= d) ? tmp[tid - d] : 0;
        __syncthreads();
        tmp[tid] += t;
        __syncthreads();
    }
    if (i < N_DST) offsets[i] = tmp[tid] - v;      // exclusive within block
    if (tid == SCAN_BLK - 1) bsums[blockIdx.x] = tmp[tid];
}

// Exclusive scan of the 98 block sums, single block.
__global__ void ia_scan_sums(int* __restrict__ bsums) {
    __shared__ int s[NB_SCAN];
    int tid = threadIdx.x;
    if (tid < NB_SCAN) s[tid] = bsums[tid];
    __syncthreads();
    if (tid == 0) {
        int run = 0;
        for (int b = 0; b < NB_SCAN; ++b) { int t = s[b]; s[b] = run; run += t; }
    }
    __syncthreads();
    if (tid < NB_SCAN) bsums[tid] = s[tid];
}

__global__ void ia_scan_add(int* __restrict__ offsets,
                            const int* __restrict__ bsums) {
    int i = blockIdx.x * blockDim.x + threadIdx.x;
    if (i < N_DST) offsets[i] += bsums[i >> 10];   // i / SCAN_BLK
    if (i == 0)    offsets[N_DST] = N_SRC;         // total is a known constant
}

__global__ void ia_fill(const int* __restrict__ idx,
                        const int* __restrict__ offsets,
                        int* __restrict__ cnt2,
                        int* __restrict__ entries) {
    int i = blockIdx.x * blockDim.x + threadIdx.x;
    if (i < N_SRC) {
        int d = idx[i];
        int p = offsets[d] + atomicAdd(&cnt2[d], 1);
        entries[p] = i;
    }
}

// ---------------- main gather: one block per destination row ----------------

__global__ __launch_bounds__(128) void ia_gather(const float4* __restrict__ x,
                                                 const float4* __restrict__ src,
                                                 const int*    __restrict__ offsets,
                                                 const int*    __restrict__ entries,
                                                 float4*       __restrict__ out) {
    int row = blockIdx.x;          // 0 .. N_DST-1
    int c   = threadIdx.x;         // 0 .. 127, one float4 per thread
    int beg = offsets[row];
    int end = offsets[row + 1];

    float4 acc = x[row * D_VEC4 + c];
    for (int e = beg; e < end; ++e) {
        int    s = entries[e];                 // wave-broadcast, L1/L2 hit
        float4 v = src[s * D_VEC4 + c];        // coalesced 2KB row read
        acc.x += v.x; acc.y += v.y; acc.z += v.z; acc.w += v.w;
    }
    out[row * D_VEC4 + c] = acc;
}

// ---------------- fallback path (previous verified version) ----------------

__global__ void IndexAdd_copy_kernel(const float4* __restrict__ x,
                                     float4* __restrict__ out, int n4) {
    int i = blockIdx.x * blockDim.x + threadIdx.x;
    if (i < n4) out[i] = x[i];
}

__global__ void IndexAdd_scatter_kernel(const float* __restrict__ src,
                                        const int* __restrict__ idx,
                                        float* __restrict__ out) {
    long long t   = (long long)blockIdx.x * blockDim.x + threadIdx.x;
    int       row = (int)(t >> 7);
    int       c4  = (int)(t & 127);
    if (row >= N_SRC) return;
    int dst = idx[row];
    float4 s = ((const float4*)(src + (long long)row * D))[c4];
    float* o = out + (long long)dst * D + (c4 << 2);
    unsafeAtomicAdd(o + 0, s.x);
    unsafeAtomicAdd(o + 1, s.y);
    unsafeAtomicAdd(o + 2, s.z);
    unsafeAtomicAdd(o + 3, s.w);
}

// ---------------- launch ----------------

extern "C" void kernel_launch(void* const* d_in, const int* in_sizes, int n_in,
                              void* d_out, int out_size, void* d_ws, size_t ws_size,
                              hipStream_t stream) {
    const float* x   = (const float*)d_in[0];
    const int*   idx = (const int*)  d_in[1];
    const float* src = (const float*)d_in[2];
    float*       out = (float*)d_out;

    // workspace layout (ints):
    //   counts  [N_DST]      (zeroed each launch)
    //   cnt2    [N_DST]      (zeroed each launch, adjacent -> one memset)
    //   offsets [N_DST + 1]
    //   bsums   [NB_SCAN]
    //   entries [N_SRC]
    const size_t need = (size_t)(3 * N_DST + 1 + NB_SCAN + N_SRC) * sizeof(int);

    if (d_ws != nullptr && ws_size >= need) {
        int* w       = (int*)d_ws;
        int* counts  = w;
        int* cnt2    = w + N_DST;
        int* offsets = w + 2 * N_DST;
        int* bsums   = offsets + (N_DST + 1);
        int* entries = bsums + NB_SCAN;

        hipMemsetAsync(counts, 0, (size_t)2 * N_DST * sizeof(int), stream);

        ia_hist      <<<(N_SRC + 255) / 256, 256, 0, stream>>>(idx, counts);
        ia_scan_block<<<NB_SCAN, SCAN_BLK,   0, stream>>>(counts, offsets, bsums);
        ia_scan_sums <<<1, 128,              0, stream>>>(bsums);
        ia_scan_add  <<<(N_DST + 255) / 256, 256, 0, stream>>>(offsets, bsums);
        ia_fill      <<<(N_SRC + 255) / 256, 256, 0, stream>>>(idx, offsets, cnt2, entries);
        ia_gather    <<<N_DST, 128,          0, stream>>>((const float4*)x,
                                                          (const float4*)src,
                                                          offsets, entries,
                                                          (float4*)out);
    } else {
        // Fallback: previous atomic version (verified at 1915 us)
        {
            int n4      = N_DST * D_VEC4;
            int threads = 256;
            int blocks  = (n4 + threads - 1) / threads;
            IndexAdd_copy_kernel<<<blocks, threads, 0, stream>>>(
                (const float4*)x, (float4*)out, n4);
        }
        {
            long long total   = (long long)N_SRC * D_VEC4;
            int       threads = 256;
            int       blocks  = (int)((total + threads - 1) / threads);
            IndexAdd_scatter_kernel<<<blocks, threads, 0, stream>>>(src, idx, out);
        }
    }
}